// Round 11
// baseline (512.061 us; speedup 1.0000x reference)
//
#include <hip/hip_runtime.h>
#include <stdint.h>

// BitNet MLP, single-pass over all 65536 tokens (7 dispatches total):
//   wabs(1) -> finalize(1) -> wquant(1) -> xquant(1) ->
//   GEMM1(int8 -> RAW z int16, exact) -> norm_quant (wave-per-row) ->
//   GEMM2(int8 -> fp32 out)
// GEMM: 128^2 tile, 4 waves, 16x16x64 i8 MFMA, conflict-free swizzle
// g^((r>>1)&3), prefetch double-buffer, launch_bounds(256,4).

typedef int v4i __attribute__((ext_vector_type(4)));

#define AS1(p) ((const __attribute__((address_space(1))) void*)(p))
#define AS3(p) ((__attribute__((address_space(3))) void*)(p))

static constexpr int MTOK = 65536;
static constexpr size_t OFF_PART = 256;                     // 512 doubles
static constexpr size_t OFF_SX   = 8192;
static constexpr size_t OFF_INV2 = OFF_SX   + 262144;       // 270336
static constexpr size_t OFF_WUQ  = OFF_INV2 + 262144;       // 532480
static constexpr size_t OFF_WDQ  = OFF_WUQ  + 1048576;      // 1581056
static constexpr size_t OFF_XQ   = OFF_WDQ  + 1048576;      // 2629632
static constexpr size_t OFF_Z16  = OFF_XQ   + 33554432;     // 36184064
static constexpr size_t OFF_HQ   = OFF_Z16  + 268435456;    // 304619520
// end = OFF_HQ + 134217728 = 438837248 (~419 MiB) < 512 MiB ws

// ---------------- weight |w| partial sums, both weights in one dispatch -----
__global__ void wabs_partial2(const float* __restrict__ wu,
                              const float* __restrict__ wd,
                              double* __restrict__ part)
{
    int t = threadIdx.x, bid = blockIdx.x;
    const float4* w4 = (const float4*)(bid < 256 ? wu : wd);
    int base = (bid & 255) * 256 + t;
    double s = 0.0;
    #pragma unroll
    for (int j = 0; j < 4; ++j) {                 // 256x256x4 = 262144 f4
        float4 v = w4[base + j * 65536];
        s += (double)fabsf(v.x) + (double)fabsf(v.y)
           + (double)fabsf(v.z) + (double)fabsf(v.w);
    }
    #pragma unroll
    for (int off = 32; off > 0; off >>= 1) s += __shfl_down(s, off);
    __shared__ double ps[4];
    int l = t & 63, wv = t >> 6;
    if (l == 0) ps[wv] = s;
    __syncthreads();
    if (t == 0) part[bid] = ((ps[0] + ps[1]) + ps[2]) + ps[3];
}

__global__ void finalize_sums(const double* __restrict__ part, double* __restrict__ sums)
{
    int t = threadIdx.x;
    double a = part[t];
    double b = part[256 + t];
    #pragma unroll
    for (int off = 32; off > 0; off >>= 1) {
        a += __shfl_down(a, off);
        b += __shfl_down(b, off);
    }
    __shared__ double pa[4], pb[4];
    int l = t & 63, wv = t >> 6;
    if (l == 0) { pa[wv] = a; pb[wv] = b; }
    __syncthreads();
    if (t == 0) {
        sums[0] = ((pa[0] + pa[1]) + pa[2]) + pa[3];
        sums[1] = ((pb[0] + pb[1]) + pb[2]) + pb[3];
    }
}

// ---------------- ternary weight quantization, both weights -----------------
__global__ void wquant2(const float* __restrict__ wu, const float* __restrict__ wd,
                        const double* __restrict__ sums,
                        signed char* __restrict__ wuq, signed char* __restrict__ wdq)
{
    int i = blockIdx.x * blockDim.x + threadIdx.x;   // 0..524287 float4 idx
    bool up = i < 262144;
    int j = up ? i : i - 262144;
    const float4* w = (const float4*)(up ? wu : wd);
    unsigned* dst   = (unsigned*)(up ? wuq : wdq);
    float mean  = (float)(up ? sums[0] : sums[1]) * (1.0f / 1048576.0f);
    float scale = 1.0f / fmaxf(mean, 1e-5f);
    float4 v = w[j];
    int q0 = (int)fminf(fmaxf(rintf(v.x * scale), -1.f), 1.f);
    int q1 = (int)fminf(fmaxf(rintf(v.y * scale), -1.f), 1.f);
    int q2 = (int)fminf(fmaxf(rintf(v.z * scale), -1.f), 1.f);
    int q3 = (int)fminf(fmaxf(rintf(v.w * scale), -1.f), 1.f);
    dst[j] = (q0 & 255) | ((q1 & 255) << 8) | ((q2 & 255) << 16) | ((q3 & 255) << 24);
}

// ---------------- activation quantization of x (per-token, H=512) -----------
__global__ void xquant(const float* __restrict__ x, signed char* __restrict__ xq,
                       float* __restrict__ inv_sx)
{
    int row = blockIdx.x * 4 + (threadIdx.x >> 6);
    int l   = threadIdx.x & 63;
    const float* xr = x + (size_t)row * 512;
    float4 v0 = *(const float4*)(xr + l * 8);
    float4 v1 = *(const float4*)(xr + l * 8 + 4);
    float m = fmaxf(fmaxf(fmaxf(fabsf(v0.x), fabsf(v0.y)), fmaxf(fabsf(v0.z), fabsf(v0.w))),
                    fmaxf(fmaxf(fabsf(v1.x), fabsf(v1.y)), fmaxf(fabsf(v1.z), fabsf(v1.w))));
    #pragma unroll
    for (int off = 1; off < 64; off <<= 1) m = fmaxf(m, __shfl_xor(m, off));
    float mc = fmaxf(m, 1e-5f);
    float s  = 127.0f / mc;
    int q[8];
    q[0] = (int)fminf(fmaxf(rintf(v0.x * s), -128.f), 127.f);
    q[1] = (int)fminf(fmaxf(rintf(v0.y * s), -128.f), 127.f);
    q[2] = (int)fminf(fmaxf(rintf(v0.z * s), -128.f), 127.f);
    q[3] = (int)fminf(fmaxf(rintf(v0.w * s), -128.f), 127.f);
    q[4] = (int)fminf(fmaxf(rintf(v1.x * s), -128.f), 127.f);
    q[5] = (int)fminf(fmaxf(rintf(v1.y * s), -128.f), 127.f);
    q[6] = (int)fminf(fmaxf(rintf(v1.z * s), -128.f), 127.f);
    q[7] = (int)fminf(fmaxf(rintf(v1.w * s), -128.f), 127.f);
    uint2 pk;
    pk.x = (q[0] & 255) | ((q[1] & 255) << 8) | ((q[2] & 255) << 16) | ((q[3] & 255) << 24);
    pk.y = (q[4] & 255) | ((q[5] & 255) << 8) | ((q[6] & 255) << 16) | ((q[7] & 255) << 24);
    *(uint2*)(xq + (size_t)row * 512 + l * 8) = pk;
    if (l == 0) inv_sx[row] = mc * (1.0f / 127.0f);
}

// ---------------- fused: stats + relu^2 + SubLN + act_quant -----------------
// ONE WAVE PER ROW (4 rows per 256-thr block): pure shfl_xor butterfly,
// no LDS, no __syncthreads.  z16 = exact int32 GEMM1 accumulator in int16.
__global__ __launch_bounds__(256)
void norm_quant(const short* __restrict__ z16, const float* __restrict__ inv_sx,
                const double* __restrict__ wsum, const float* __restrict__ g,
                signed char* __restrict__ hq, float* __restrict__ inv2)
{
    int row = blockIdx.x * 4 + (threadIdx.x >> 6);
    int l   = threadIdx.x & 63;
    float wmean = fmaxf((float)wsum[0] * (1.0f / 1048576.0f), 1e-5f);
    float f = inv_sx[row] * wmean;

    const short* zr = z16 + (size_t)row * 2048;
    float hg[32];                       // h*g per element
    float ss = 0.f, mm = 0.f;
    #pragma unroll
    for (int j = 0; j < 4; ++j) {
        int cols = j * 512 + l * 8;
        v4i zi = *(const v4i*)(zr + cols);          // 8 int16
        const short* zs = (const short*)&zi;
        float4 g0 = *(const float4*)(g + cols);
        float4 g1 = *(const float4*)(g + cols + 4);
        float gv[8] = {g0.x, g0.y, g0.z, g0.w, g1.x, g1.y, g1.z, g1.w};
        #pragma unroll
        for (int e = 0; e < 8; ++e) {
            float z = (float)zs[e] * f;
            float a = fmaxf(z, 0.f);
            float h = a * a;
            ss += h * h;
            float y = h * gv[e];
            hg[j * 8 + e] = y;
            mm = fmaxf(mm, fabsf(y));
        }
    }
    #pragma unroll
    for (int off = 1; off < 64; off <<= 1) {
        ss += __shfl_xor(ss, off);
        mm  = fmaxf(mm, __shfl_xor(mm, off));
    }
    float var  = ss * (1.0f / 2048.0f);
    float r    = 1.0f / sqrtf(var + 1e-6f);
    float maxy = fmaxf(r * mm, 1e-5f);
    float sc   = 127.0f / maxy;
    if (l == 0) inv2[row] = maxy * (1.0f / 127.0f);

    #pragma unroll
    for (int j = 0; j < 4; ++j) {
        int q[8];
        #pragma unroll
        for (int e = 0; e < 8; ++e) {
            float y = hg[j * 8 + e] * r;
            q[e] = (int)fminf(fmaxf(rintf(y * sc), -128.f), 127.f);
        }
        uint2 pk;
        pk.x = (q[0] & 255) | ((q[1] & 255) << 8) | ((q[2] & 255) << 16) | ((q[3] & 255) << 24);
        pk.y = (q[4] & 255) | ((q[5] & 255) << 8) | ((q[6] & 255) << 16) | ((q[7] & 255) << 24);
        *(uint2*)(hq + (size_t)row * 2048 + j * 512 + l * 8) = pk;
    }
}

// ---------------- int8 GEMM: C[M,N] = A[M,K] * B[N,K]^T ---------------------
// Prefetch double-buffer, one __syncthreads per K-step (vmcnt drain = wait).
// EPI 0: raw acc -> int16 via LDS transpose.  EPI 2: dequant -> fp32.
template<int K, int N, int EPI>
__global__ __launch_bounds__(256, 4)
void gemm_i8(const signed char* __restrict__ A,
             const signed char* __restrict__ B,
             const float* __restrict__ rowscale,   // inv2 (EPI2)
             const double* __restrict__ wsum,
             short* __restrict__ z16,
             float* __restrict__ out)
{
    constexpr int NKT = K / 64;
    constexpr int NBN = N / 128;
    __shared__ __align__(16) char smem[32768];     // 2 bufs x (A 8K + B 8K)

    // bijective XCD-chunked swizzle (m204); N-inner so chunks share A panels
    int nwg  = gridDim.x;
    int orig = blockIdx.x;
    int q8 = nwg >> 3, r8 = nwg & 7;
    int xcd = orig & 7, lin = orig >> 3;
    int swz = (xcd < r8 ? xcd * (q8 + 1) : r8 * (q8 + 1) + (xcd - r8) * q8) + lin;
    int mt = swz / NBN, nt = swz - mt * NBN;

    size_t mbase = (size_t)mt * 128;
    int    nbase = nt * 128;

    int t = threadIdx.x;
    int l = t & 63;
    int wid = t >> 6;
    int wr = wid >> 1, wc = wid & 1;

    v4i acc[4][4] = {};

    const signed char* Ab = A + mbase * K;
    const signed char* Bb = B + (size_t)nbase * K;

    auto stage = [&](int p, int kt) {
        char* lA = smem + p * 16384;
        char* lB = lA + 8192;
        int k0 = kt * 64;
        #pragma unroll
        for (int i = 0; i < 2; ++i) {
            int lin16 = i * 256 + t;
            int row   = lin16 >> 2;
            int c     = (lin16 & 3) ^ ((row >> 1) & 3);
            __builtin_amdgcn_global_load_lds(AS1(Ab + (size_t)row * K + k0 + c * 16),
                                             AS3(lA + lin16 * 16), 16, 0, 0);
            __builtin_amdgcn_global_load_lds(AS1(Bb + (size_t)row * K + k0 + c * 16),
                                             AS3(lB + lin16 * 16), 16, 0, 0);
        }
    };

    stage(0, 0);
    __syncthreads();                               // tile 0 landed

    for (int kt = 0; kt < NKT; ++kt) {
        int p = kt & 1;
        if (kt + 1 < NKT) stage(p ^ 1, kt + 1);    // prefetch next tile
        const char* lA = smem + p * 16384;
        const char* lB = lA + 8192;
        v4i af[4], bf[4];
        #pragma unroll
        for (int r = 0; r < 4; ++r) {
            int arow = wr * 64 + r * 16 + (l & 15);
            int ac   = (l >> 4) ^ ((arow >> 1) & 3);
            af[r] = *reinterpret_cast<const v4i*>(lA + (arow * 4 + ac) * 16);
            int brow = wc * 64 + r * 16 + (l & 15);
            int bc   = (l >> 4) ^ ((brow >> 1) & 3);
            bf[r] = *reinterpret_cast<const v4i*>(lB + (brow * 4 + bc) * 16);
        }
        #pragma unroll
        for (int r = 0; r < 4; ++r)
            #pragma unroll
            for (int c = 0; c < 4; ++c)
                acc[r][c] = __builtin_amdgcn_mfma_i32_16x16x64_i8(af[r], bf[c], acc[r][c], 0, 0, 0);
        __syncthreads();                           // drains vmcnt: prefetch landed
    }

    int rsub = wr * 64 + 4 * (l >> 4);   // + rt*16 + reg  -> local row
    int csub = wc * 64 + (l & 15);       // + ct*16        -> local col

    if constexpr (EPI == 0) {
        // raw int16 z via LDS transpose -> coalesced 16B stores
        short* sm = (short*)smem;
        #pragma unroll
        for (int rt = 0; rt < 4; ++rt)
            #pragma unroll
            for (int reg = 0; reg < 4; ++reg) {
                int rho = rsub + rt * 16 + reg;
                #pragma unroll
                for (int ct = 0; ct < 4; ++ct)
                    sm[rho * 128 + csub + ct * 16] = (short)acc[rt][ct][reg];
            }
        __syncthreads();
        #pragma unroll
        for (int it = 0; it < 8; ++it) {
            int j = it * 256 + t;
            int rho = j >> 4, ck = j & 15;
            *(v4i*)(z16 + (size_t)(mbase + rho) * 2048 + nbase + ck * 8) =
                *(const v4i*)(sm + rho * 128 + ck * 8);
        }
    } else {
        float wmean = fmaxf((float)wsum[0] * (1.0f / 1048576.0f), 1e-5f);
        #pragma unroll
        for (int rt = 0; rt < 4; ++rt)
            #pragma unroll
            for (int reg = 0; reg < 4; ++reg) {
                size_t grow = mbase + rsub + rt * 16 + reg;
                float f = rowscale[grow] * wmean;
                #pragma unroll
                for (int ct = 0; ct < 4; ++ct)
                    out[grow * N + nbase + csub + ct * 16] = (float)acc[rt][ct][reg] * f;
            }
    }
}

// ---------------------------------------------------------------------------
extern "C" void kernel_launch(void* const* d_in, const int* in_sizes, int n_in,
                              void* d_out, int out_size, void* d_ws, size_t ws_size,
                              hipStream_t stream)
{
    const float* x  = (const float*)d_in[0];
    const float* wu = (const float*)d_in[1];
    const float* wd = (const float*)d_in[2];
    const float* g  = (const float*)d_in[3];
    float* out = (float*)d_out;
    char*  ws  = (char*)d_ws;

    double* sums     = (double*)ws;
    double* part     = (double*)(ws + OFF_PART);    // 512 doubles
    float*  inv_sx   = (float*)(ws + OFF_SX);
    float*  inv2     = (float*)(ws + OFF_INV2);
    signed char* wuq = (signed char*)(ws + OFF_WUQ);
    signed char* wdq = (signed char*)(ws + OFF_WDQ);
    signed char* xq  = (signed char*)(ws + OFF_XQ);
    short*  z16      = (short*)(ws + OFF_Z16);
    signed char* hq  = (signed char*)(ws + OFF_HQ);

    wabs_partial2<<<512, 256, 0, stream>>>(wu, wd, part);
    finalize_sums<<<1, 256, 0, stream>>>(part, sums);
    wquant2<<<2048, 256, 0, stream>>>(wu, wd, sums, wuq, wdq);
    xquant<<<16384, 256, 0, stream>>>(x, xq, inv_sx);

    // GEMM1: z = xq @ wuq^T (raw int16, exact)
    gemm_i8<512, 2048, 0><<<(MTOK / 128) * 16, 256, 0, stream>>>(
        xq, wuq, nullptr, nullptr, z16, nullptr);
    // fused stats + relu^2 + SubLN + act_quant (wave-per-row)
    norm_quant<<<MTOK / 4, 256, 0, stream>>>(z16, inv_sx, sums, g, hq, inv2);
    // GEMM2: out = hq @ wdq^T, dequant
    gemm_i8<2048, 512, 2><<<(MTOK / 128) * 4, 256, 0, stream>>>(
        hq, wdq, inv2, sums + 1, nullptr, out);
}